// Round 15
// baseline (724.806 us; speedup 1.0000x reference)
//
#include <hip/hip_runtime.h>
#include <hip/hip_bf16.h>
#include <stdint.h>

#define N_NODES 10000
#define N_EDGES 320000

using bf16x8 = __attribute__((ext_vector_type(8))) short;
using fp32x4 = __attribute__((ext_vector_type(4))) float;
using u16x8 = __attribute__((ext_vector_type(8))) unsigned short;
using u16x4 = __attribute__((ext_vector_type(4))) unsigned short;
using i32x4 = __attribute__((ext_vector_type(4))) int;

__device__ __forceinline__ float bf2f(unsigned short u) {
  union { unsigned int i; float f; } v; v.i = ((unsigned int)u) << 16; return v.f;
}
__device__ __forceinline__ unsigned short f2bf(float f) {
  union { float f; unsigned int i; } v; v.f = f;
  unsigned int x = v.i;
  x += 0x7fffu + ((x >> 16) & 1u);
  return (unsigned short)(x >> 16);
}
// Packed f32x2 -> bf16x2 via v_cvt_pk_bf16_f32 (RNE, same rounding as f2bf).
__device__ __forceinline__ unsigned int f2bf_pk(float lo, float hi) {
  __hip_bfloat162 h = __float22bfloat162_rn(float2{lo, hi});
  union { __hip_bfloat162 h; unsigned int u; } cv; cv.h = h; return cv.u;
}
// Fast sigmoid: raw v_rcp_f32 (~1ulp) -- fine vs 0.03 absmax tolerance.
__device__ __forceinline__ float fsigmoid(float x) {
  return __builtin_amdgcn_rcpf(1.f + __expf(-x));
}

// ---------------- internal bf16 arena (element offsets) ---------------------
#define A_POS 0
#define A_EA 20000
#define A_WP 340000
#define A_BP 340512
#define A_WA 340768
#define A_BA 341024
#define A_W1 341280
#define A_B1 537888
#define A_W2 538656
#define A_B2 735264
#define A_WE 736032
#define A_BE 998176
#define A_WS 999200
#define A_WT 1261344
#define A_WM1 1523488
#define A_BM1 1556384
#define A_AL 1556512
#define A_WM2 1556544
#define A_BM2 1556672
#define ARENA_USED 1556673
#define ARENA_TOT 1556736

__constant__ int g_off[19] = {A_POS, A_EA, A_WP, A_BP, A_WA, A_BA, A_W1, A_B1,
                              A_W2, A_B2, A_WE, A_BE, A_WS, A_WT, A_WM1,
                              A_BM1, A_AL, A_WM2, A_BM2};

struct Ptrs { const void* p[19]; };

// Dtype detector (block 0) + deg zeroing (all blocks).
__global__ void k_detect(const unsigned short* wpraw, int* flag, int* deg) {
  int i = blockIdx.x * 256 + threadIdx.x;
  if (i < N_NODES) deg[i] = 0;
  if (blockIdx.x == 0) {
    __shared__ int cnt;
    int tid = threadIdx.x;
    if (tid == 0) cnt = 0;
    __syncthreads();
    float v0 = bf2f(wpraw[tid]);
    float v1 = bf2f(wpraw[256 + tid]);
    int big = (fabsf(v0) > 100.f ? 1 : 0) + (fabsf(v1) > 100.f ? 1 : 0);
    atomicAdd(&cnt, big);
    __syncthreads();
    if (tid == 0) *flag = (cnt > 10) ? 1 : 0;  // 1 = fp32 inputs
  }
}

// Normalize all float inputs into the bf16 arena (flattened grid).
// Round 15: k_hist FOLDED IN (edge indices 0..N_EDGES-1 are all < ARENA_USED;
// deg zeroed by the earlier k_detect launch) -- saves one launch.
__global__ void k_cast(Ptrs ptrs, const int* __restrict__ flag,
                       unsigned short* __restrict__ arena,
                       const int* __restrict__ dstA, int* __restrict__ deg) {
  int a = blockIdx.x * 256 + threadIdx.x;
  if (a >= ARENA_USED) return;
  if (a < N_EDGES) {
    int d = dstA[a];
    if ((unsigned)d < N_NODES) atomicAdd(&deg[d], 1);
  }
  int z = 0;
#pragma unroll
  for (int j = 1; j < 19; ++j) if (a >= g_off[j]) z = j;
  int i = a - g_off[z];
  float v;
  if (*flag) v = ((const float*)ptrs.p[z])[i];
  else       v = bf2f(((const unsigned short*)ptrs.p[z])[i]);
  arena[a] = f2bf(v);
}

// ---------------------------------------------------------------------------
// Weight prep: transpose [K,N] -> n-major [N,K] (row = out-col, 512B rows).
// nodeBT per layer l<3: [W1T|W2T|WsT|WtT] (1024x256); l==3: [WsT|WtT].
// ---------------------------------------------------------------------------
__global__ void k_prep(const unsigned short* __restrict__ arena,
                       unsigned short* nodeBT, unsigned short* WeT,
                       unsigned short* Wm1T, unsigned short* biascat) {
  int z = blockIdx.z;
  int i = blockIdx.x * 256 + threadIdx.x;
  if (z == 19) {  // bias concat: 3 x [b1|b2|0|0] (1024) then 512 zeros
    if (i < 3072) {
      int l = i >> 10, j = i & 1023;
      unsigned short v = 0;
      if (j < 256) v = arena[A_B1 + l * 256 + j];
      else if (j < 512) v = arena[A_B2 + l * 256 + (j - 256)];
      biascat[i] = v;
    } else if (i < 3584) {
      biascat[i] = 0;
    }
    return;
  }
  const unsigned short* src; unsigned short* dst; int srcN = 256;
  if (z < 3)       {                 src = arena + A_W1 + z * 65536; dst = nodeBT + z * 262144; }
  else if (z < 6)  { int l = z - 3;  src = arena + A_W2 + l * 65536; dst = nodeBT + l * 262144 + 65536; }
  else if (z < 10) { int l = z - 6;  src = arena + A_WS + l * 65536;
                     dst = (l < 3) ? nodeBT + l * 262144 + 131072 : nodeBT + 786432; }
  else if (z < 14) { int l = z - 10; src = arena + A_WT + l * 65536;
                     dst = (l < 3) ? nodeBT + l * 262144 + 196608 : nodeBT + 786432 + 65536; }
  else if (z < 18) { int l = z - 14; src = arena + A_WE + l * 65536; dst = WeT + l * 65536; }
  else             { src = arena + A_WM1; dst = Wm1T; srcN = 128; }
  if (i < srcN * 256) {
    int k = i & 255, n = i >> 8;
    dst[i] = src[k * srcN + n];  // dst[n][k] = src[k][n]
  }
}

// ---------------------------------------------------------------------------
// Fragment pack, ALL THREE weight families in one launch (round 15: was 3
// launches; pure grid concatenation, identical per-region math).
// ---------------------------------------------------------------------------
#define PK_NODE 114688
#define PK_WE   32768
#define PK_WM1  4096
__global__ void k_pack_all(const unsigned short* __restrict__ nodeBT,
                           unsigned short* __restrict__ nodeBTp,
                           const unsigned short* __restrict__ WeT,
                           unsigned short* __restrict__ WeTp,
                           const unsigned short* __restrict__ Wm1T,
                           unsigned short* __restrict__ Wm1Tp) {
  int gc = blockIdx.x * 256 + threadIdx.x;
  const unsigned short* src; unsigned short* dst; int MT; int c;
  if (gc < PK_NODE)                { src = nodeBT; dst = nodeBTp; MT = 4; c = gc; }
  else if (gc < PK_NODE + PK_WE)   { src = WeT;  dst = WeTp;  MT = 4; c = gc - PK_NODE; }
  else if (gc < PK_NODE + PK_WE + PK_WM1)
                                   { src = Wm1T; dst = Wm1Tp; MT = 2; c = gc - PK_NODE - PK_WE; }
  else return;
  int perg = MT * 512;               // 16B chunks per group
  int g = c / perg, r = c % perg;
  int ks = r / (64 * MT);
  int rem = r % (64 * MT);
  int mt = rem >> 6, lane = rem & 63;
  int q = lane >> 4, ll = lane & 15;
  int oc = g * (MT * 16) + (ll >> 2) * (MT * 4) + (ll & 3) + mt * 4;
  i32x4 v = *(const i32x4*)((const char*)src + ((long)oc << 9) + (ks << 6) + (q << 4));
  ((i32x4*)dst)[c] = v;
}

// x0 = pos @ Wp + bp (K=2), fp32 master; zeroes BOTH agg buffers.
__global__ void k_init_x(const unsigned short* __restrict__ arena,
                         float* __restrict__ xf, float* __restrict__ aggA,
                         float* __restrict__ aggB) {
  int n = blockIdx.x, c = threadIdx.x;
  float p0 = bf2f(arena[A_POS + 2 * n]), p1 = bf2f(arena[A_POS + 2 * n + 1]);
  float v = fmaf(p0, bf2f(arena[A_WP + c]),
                 fmaf(p1, bf2f(arena[A_WP + 256 + c]), bf2f(arena[A_BP + c])));
  long idx = ((long)n << 8) + c;
  xf[idx] = v;
  aggA[idx] = 0.f;
  aggB[idx] = 0.f;
}

__global__ void k_scan(const int* __restrict__ deg, int* __restrict__ rowptr,
                       int* __restrict__ cursor) {
  __shared__ int part[256];
  int tid = threadIdx.x;
  int base = tid * 40;
  int s = 0;
  for (int i = 0; i < 40; ++i) {
    int idx = base + i;
    if (idx < N_NODES) s += deg[idx];
  }
  part[tid] = s;
  __syncthreads();
  if (tid == 0) {
    int run = 0;
    for (int i = 0; i < 256; ++i) { int t = part[i]; part[i] = run; run += t; }
    rowptr[N_NODES] = run;
  }
  __syncthreads();
  int run = part[tid];
  for (int i = 0; i < 40; ++i) {
    int idx = base + i;
    if (idx < N_NODES) { rowptr[idx] = run; cursor[idx] = run; run += deg[idx]; }
  }
}

// Also emits csrc/cdst (endpoints in CSR order) and eaC (ea gathered to CSR).
__global__ void k_fill(const int* __restrict__ dstA, const int* __restrict__ srcA,
                       const unsigned short* __restrict__ arena,
                       int* __restrict__ cursor, int* __restrict__ eid,
                       int* __restrict__ csrc, int* __restrict__ cdst,
                       unsigned short* __restrict__ eaC) {
  int i = blockIdx.x * 256 + threadIdx.x;
  if (i < N_EDGES) {
    int d = dstA[i]; if ((unsigned)d >= N_NODES) d = 0;
    int p = atomicAdd(&cursor[d], 1);
    if ((unsigned)p < N_EDGES) {
      eid[p] = i;
      int s = srcA[i]; if ((unsigned)s >= N_NODES) s = 0;
      csrc[p] = s;
      cdst[p] = d;
      eaC[p] = arena[A_EA + i];
    }
  }
}

// ---------------------------------------------------------------------------
// Round 15 = round-14 (best: 720.7us) + (a) edge01 agg batch 8->4 (frees ~8
// VGPRs: evv/x2v arrays halved; absorbs fsigmoid's pressure -> kill the ~100MB
// residual scratch spill seen in r13/r14 WRITE_SIZE), (b) k_hist folded into
// k_cast, (c) 3 k_pack launches merged into k_pack_all.
// HARD RULE (r4/r6/r10/r12/r13): no widened temporaries or register-resident
// prefetch in the edge kernels; scalar epilogue only.
// ---------------------------------------------------------------------------
#define SM_PITCH 528
#define XS_PITCH 144
#define EROWS 80
#define ECHUNKS 5
#define EDGE_BLOCKS (N_EDGES / EROWS)   // 4000

template <bool NT, int ROWS, int BLK>
__device__ __forceinline__ void stage_tile(char* smc, const unsigned short* src,
                                           long rowBase) {
  int tid = threadIdx.x;
#pragma unroll
  for (int it = 0; it < ROWS * 32 / BLK; ++it) {   // ROWS rows x 32 groups of 16B
    int lin = it * BLK + tid;
    int row = lin >> 5, g = lin & 31;
    const i32x4* p = (const i32x4*)((const char*)src + ((rowBase + row) << 9) + (g << 4));
    i32x4 v = NT ? __builtin_nontemporal_load(p) : *p;
    *(i32x4*)(smc + row * SM_PITCH + (g << 4)) = v;
  }
}

template <int MT, int NTT>
__device__ __forceinline__ void gemm_swap(const char* smc, const unsigned short* WTp,
                                          int colBase, fp32x4 (&acc)[MT][NTT]) {
  const int lane = threadIdx.x & 63;
  const int q = lane >> 4, ll = lane & 15;
  const char* wbase = (const char*)WTp + ((long)colBase << 9) + (lane << 4);
  __builtin_amdgcn_s_setprio(1);
#pragma unroll
  for (int ks = 0; ks < 8; ++ks) {
    bf16x8 a[MT];
#pragma unroll
    for (int mt = 0; mt < MT; ++mt)
      a[mt] = *(const bf16x8*)(wbase + ((long)(ks * MT + mt) << 10));
    bf16x8 b[NTT];
#pragma unroll
    for (int nt = 0; nt < NTT; ++nt)
      b[nt] = *(const bf16x8*)(smc + (nt * 16 + ll) * SM_PITCH + (ks << 6) + (q << 4));
#pragma unroll
    for (int mt = 0; mt < MT; ++mt)
#pragma unroll
      for (int nt = 0; nt < NTT; ++nt)
        acc[mt][nt] = __builtin_amdgcn_mfma_f32_16x16x32_bf16(a[mt], b[nt], acc[mt][nt], 0, 0, 0);
  }
  __builtin_amdgcn_s_setprio(0);
}

// ---------------------------------------------------------------------------
// Edge epilogue with COALESCED xs gather (1-chunk-ahead LDS bounce pipeline);
// xt direct. e_new = e_old + relu(acc + xs + xt + be), in-place in LDS tile.
// Output packing via v_cvt_pk_bf16_f32. (scalar round-9 version, scratch-free)
// ---------------------------------------------------------------------------
template <int NTT>
__device__ __forceinline__ void edge_epilogue_cx(
    char* smc, char* xsw, const fp32x4 (&acc)[4][NTT], const int* s_src,
    const int* s_dst, const unsigned short* XW, int xw_pitch, int xs_off,
    int xt_off, const unsigned short* bePtr, int colBase, int lane) {
  const int q = lane >> 4, ll = lane & 15;
  const int cb = colBase + q * 16;
  u16x8 be0 = *(const u16x8*)(bePtr + cb);
  u16x8 be1 = *(const u16x8*)(bePtr + cb + 8);
  const int prow = lane >> 3;          // row within half-chunk (0..7)
  const int ppc = lane & 7;            // 16B piece within row
  const int pcol = xs_off + colBase + ppc * 8;
  u16x8 pfA = *(const u16x8*)(XW + (long)s_src[prow] * xw_pitch + pcol);
  u16x8 pfB = *(const u16x8*)(XW + (long)s_src[8 + prow] * xw_pitch + pcol);
#pragma unroll
  for (int nt = 0; nt < NTT; ++nt) {
    *(u16x8*)(xsw + prow * XS_PITCH + ppc * 16) = pfA;
    *(u16x8*)(xsw + (8 + prow) * XS_PITCH + ppc * 16) = pfB;
    if (nt + 1 < NTT) {   // issue next chunk's gathers; they fly under compute
      int elA = (nt + 1) * 16 + prow;
      pfA = *(const u16x8*)(XW + (long)s_src[elA] * xw_pitch + pcol);
      pfB = *(const u16x8*)(XW + (long)s_src[elA + 8] * xw_pitch + pcol);
    }
    int el = nt * 16 + ll;
    int dn = s_dst[el];
    const unsigned short* xtrow = XW + (long)dn * xw_pitch + xt_off + cb;
    u16x8 xt0 = *(const u16x8*)(xtrow);
    u16x8 xt1 = *(const u16x8*)(xtrow + 8);
    u16x8 xs0 = *(const u16x8*)(xsw + ll * XS_PITCH + q * 32);
    u16x8 xs1 = *(const u16x8*)(xsw + ll * XS_PITCH + q * 32 + 16);
    u16x8* slot = (u16x8*)(smc + el * SM_PITCH + cb * 2);
    u16x8 er0 = slot[0], er1 = slot[1];
    float f[16];
#pragma unroll
    for (int mt = 0; mt < 4; ++mt)
#pragma unroll
      for (int r = 0; r < 4; ++r) {
        int i = mt * 4 + r;
        float xsv = bf2f(i < 8 ? xs0[i] : xs1[i - 8]);
        float xtv = bf2f(i < 8 ? xt0[i] : xt1[i - 8]);
        float erv = bf2f(i < 8 ? er0[i] : er1[i - 8]);
        float bev = bf2f(i < 8 ? be0[i] : be1[i - 8]);
        float v = acc[mt][nt][r] + xsv + xtv + bev;
        v = fmaxf(v, 0.f);
        f[i] = erv + v;
      }
    union { u16x8 v; unsigned int w[4]; } O0, O1;
#pragma unroll
    for (int p = 0; p < 4; ++p) {
      O0.w[p] = f2bf_pk(f[2 * p], f[2 * p + 1]);
      O1.w[p] = f2bf_pk(f[8 + 2 * p], f[9 + 2 * p]);
    }
    slot[0] = O0.v;
    slot[1] = O1.v;  // slot owned by this lane only
  }
}

// ---------------------------------------------------------------------------
// Fused layers-0+1 edge kernel (80-row tiles, 3 blocks/CU): build e0 from
// eaC; edge(0) -> e1 in LDS; agg(1) from the e1 tile (single-chain scan,
// 4-wide batches, run-batched atomics into aggB); edge(1) -> e2 in LDS;
// write e2. e1 never hits HBM.
// ---------------------------------------------------------------------------
__global__ __launch_bounds__(256, 3) void k_edge01(
    unsigned short* __restrict__ e, const unsigned short* __restrict__ WeT0,
    const unsigned short* __restrict__ WeT1,
    const unsigned short* __restrict__ XWa, const unsigned short* __restrict__ XWb,
    const unsigned short* __restrict__ arena, const unsigned short* __restrict__ eaC,
    const int* __restrict__ csrc, const int* __restrict__ cdst,
    float* __restrict__ agg) {
  __shared__ int4 sm4[EROWS * 33];
  __shared__ int4 xsb4[4 * 2304 / 16];
  __shared__ int s_src[EROWS];
  __shared__ int s_dst[EROWS];
  char* smc = (char*)sm4;
  const long tileBase = (long)blockIdx.x * EROWS;
  const int tid = threadIdx.x;
  const int wave = tid >> 6, lane = tid & 63;
  const int colBase = wave * 64;
  char* xsw = (char*)xsb4 + wave * 2304;

  // ---- build e0 = ea*Wa + ba in LDS ----
#pragma unroll
  for (int it = 0; it < EROWS * 32 / 256; ++it) {
    int lin = it * 256 + tid;
    int row = lin >> 5, g = lin & 31;
    float eav = bf2f(eaC[tileBase + row]);
    int c0 = g * 8;
    float f[8];
#pragma unroll
    for (int j = 0; j < 8; ++j)
      f[j] = fmaf(eav, bf2f(arena[A_WA + c0 + j]), bf2f(arena[A_BA + c0 + j]));
    union { bf16x8 v; unsigned int w[4]; } O;
#pragma unroll
    for (int p = 0; p < 4; ++p) O.w[p] = f2bf_pk(f[2 * p], f[2 * p + 1]);
    *(bf16x8*)(smc + row * SM_PITCH + (g << 4)) = O.v;
  }
  if (tid < EROWS) {
    long edge = tileBase + tid;
    int s = csrc[edge]; if ((unsigned)s >= N_NODES) s = 0;
    int d = cdst[edge]; if ((unsigned)d >= N_NODES) d = 0;
    s_src[tid] = s;
    s_dst[tid] = d;
  }
  __syncthreads();

  // ---- edge update l=0 -> e1 in LDS ----
  fp32x4 acc[4][ECHUNKS];
#pragma unroll
  for (int mt = 0; mt < 4; ++mt)
#pragma unroll
    for (int nt = 0; nt < ECHUNKS; ++nt) acc[mt][nt] = 0.f;
  gemm_swap<4, ECHUNKS>(smc, WeT0, colBase, acc);
  __syncthreads();
  edge_epilogue_cx<ECHUNKS>(smc, xsw, acc, s_src, s_dst, XWa, 1024, 512, 768,
                            arena + A_BE, colBase, lane);
  __syncthreads();  // e1 complete in LDS

  // ---- agg(1): gate(e1) * (x1@W2+b2)[src], run-batched atomics ----
  // 4-wide batches (was 8): halves the live staging arrays -> frees ~8 VGPRs
  // at the hard 84-reg cap, absorbing fsigmoid's pressure (r14 spill tell).
  {
    const int c = tid;           // column 0..255
    float a = 0.f;
    int run = s_dst[0];
    for (int b4 = 0; b4 < EROWS; b4 += 4) {
      float evv[4], x2v[4];
#pragma unroll
      for (int j = 0; j < 4; ++j) {
        int row = b4 + j;
        evv[j] = bf2f(*(const unsigned short*)(smc + row * SM_PITCH + c * 2));
        x2v[j] = bf2f(XWb[(long)s_src[row] * 1024 + 256 + c]);
      }
#pragma unroll
      for (int j = 0; j < 4; ++j) {
        int d = s_dst[b4 + j];
        if (d != run) {  // uniform across the block (dst-sorted)
          atomicAdd(&agg[((long)run << 8) + c], a);
          a = 0.f;
          run = d;
        }
        a = fmaf(fsigmoid(evv[j]), x2v[j], a);
      }
    }
    atomicAdd(&agg[((long)run << 8) + c], a);
  }

  // ---- edge update l=1 -> e2 in LDS ----
#pragma unroll
  for (int mt = 0; mt < 4; ++mt)
#pragma unroll
    for (int nt = 0; nt < ECHUNKS; ++nt) acc[mt][nt] = 0.f;
  gemm_swap<4, ECHUNKS>(smc, WeT1, colBase, acc);
  __syncthreads();  // all waves done reading e1 tile before in-place update
  edge_epilogue_cx<ECHUNKS>(smc, xsw, acc, s_src, s_dst, XWb, 1024, 512, 768,
                            arena + A_BE + 256, colBase, lane);
  __syncthreads();  // e2 complete in LDS

  // ---- writeback e2 ----
#pragma unroll
  for (int it = 0; it < EROWS * 32 / 256; ++it) {
    int lin = it * 256 + tid;
    int row = lin >> 5, g = lin & 31;
    i32x4 v = *(const i32x4*)(smc + row * SM_PITCH + (g << 4));
    __builtin_nontemporal_store(v, (i32x4*)((char*)e + ((tileBase + row) << 9) + (g << 4)));
  }
}

// ---------------------------------------------------------------------------
// Fused last-2 edge kernel (80-row tiles, 3 blocks/CU): stage e2;
// edge-update(l=2) -> e3 in LDS; edge-update(l=3) -> e4 in LDS; fused MLP
// head -> out. e3/e4 never hit HBM.
// ---------------------------------------------------------------------------
__global__ __launch_bounds__(256, 3) void k_edge_last2(
    const unsigned short* __restrict__ e, const unsigned short* __restrict__ WeT2,
    const unsigned short* __restrict__ WeT3,
    const unsigned short* __restrict__ XW2, const unsigned short* __restrict__ XW3,
    const unsigned short* __restrict__ arena, const unsigned short* __restrict__ eaC,
    const int* __restrict__ csrc, const int* __restrict__ cdst,
    const unsigned short* __restrict__ Wm1T, const int* __restrict__ eid,
    const int* __restrict__ flag, void* __restrict__ out) {
  __shared__ int4 sm4[EROWS * 33];
  __shared__ int4 xsb4[4 * 2304 / 16];
  __shared__ int s_src[EROWS];
  __shared__ int s_dst[EROWS];
  __shared__ float part[EROWS * 4];
  char* smc = (char*)sm4;
  const long tileBase = (long)blockIdx.x * EROWS;
  const int tid = threadIdx.x;
  const int wave = tid >> 6, lane = tid & 63;
  const int q = lane >> 4, ll = lane & 15;
  const int colBase = wave * 64;
  char* xsw = (char*)xsb4 + wave * 2304;

  stage_tile<true, EROWS, 256>(smc, e, tileBase);
  if (tid < EROWS) {
    long edge = tileBase + tid;
    int s = csrc[edge]; if ((unsigned)s >= N_NODES) s = 0;
    int d = cdst[edge]; if ((unsigned)d >= N_NODES) d = 0;
    s_src[tid] = s;
    s_dst[tid] = d;
  }
  __syncthreads();

  // ---- edge update l=2 ----
  fp32x4 acc[4][ECHUNKS];
#pragma unroll
  for (int mt = 0; mt < 4; ++mt)
#pragma unroll
    for (int nt = 0; nt < ECHUNKS; ++nt) acc[mt][nt] = 0.f;
  gemm_swap<4, ECHUNKS>(smc, WeT2, colBase, acc);
  __syncthreads();
  edge_epilogue_cx<ECHUNKS>(smc, xsw, acc, s_src, s_dst, XW2, 1024, 512, 768,
                            arena + A_BE + 2 * 256, colBase, lane);
  __syncthreads();  // e3 complete in LDS

  // ---- edge update l=3 ----
#pragma unroll
  for (int mt = 0; mt < 4; ++mt)
#pragma unroll
    for (int nt = 0; nt < ECHUNKS; ++nt) acc[mt][nt] = 0.f;
  gemm_swap<4, ECHUNKS>(smc, WeT3, colBase, acc);
  __syncthreads();
  edge_epilogue_cx<ECHUNKS>(smc, xsw, acc, s_src, s_dst, XW3, 512, 0, 256,
                            arena + A_BE + 3 * 256, colBase, lane);
  __syncthreads();  // e4 complete in LDS

  // ---- fused MLP head (128 out-cols over 4 waves: 32 cols/wave) ----
  fp32x4 acc2[2][ECHUNKS];
#pragma unroll
  for (int mt = 0; mt < 2; ++mt)
#pragma unroll
    for (int nt = 0; nt < ECHUNKS; ++nt) acc2[mt][nt] = 0.f;
  const int colBase2 = wave * 32;
  gemm_swap<2, ECHUNKS>(smc, Wm1T, colBase2, acc2);

  const int cb2 = colBase2 + q * 8;
  float alphaf = bf2f(arena[A_AL]);
  float bmc[8], wl[8], w2c[8];
#pragma unroll
  for (int i = 0; i < 8; ++i) {
    bmc[i] = bf2f(arena[A_BM1 + cb2 + i]);
    wl[i] = bf2f(arena[A_WM1 + 32768 + cb2 + i]);
    w2c[i] = bf2f(arena[A_WM2 + cb2 + i]);
  }
#pragma unroll
  for (int nt = 0; nt < ECHUNKS; ++nt) {
    int el = nt * 16 + ll;
    float eav = bf2f(eaC[tileBase + el]);
    float ps = 0.f;
#pragma unroll
    for (int mt = 0; mt < 2; ++mt)
#pragma unroll
      for (int r = 0; r < 4; ++r) {
        int i = mt * 4 + r;
        float h = acc2[mt][nt][r] + bmc[i] + eav * wl[i];
        h = (h > 0.f) ? h : alphaf * h;
        ps += h * w2c[i];
      }
    ps += __shfl_xor(ps, 16, 64);
    ps += __shfl_xor(ps, 32, 64);
    if (q == 0) part[el * 4 + wave] = ps;
  }
  __syncthreads();
  if (tid < EROWS) {
    float t = part[tid * 4] + part[tid * 4 + 1] + part[tid * 4 + 2] + part[tid * 4 + 3]
            + bf2f(arena[A_BM2]);
    long row = tileBase + tid;
    int oe = eid[row]; if ((unsigned)oe >= N_EDGES) oe = 0;
    if (*flag) ((float*)out)[oe] = t;
    else       ((unsigned short*)out)[oe] = f2bf(t);
  }
}

// ---------------------------------------------------------------------------
// Fused node kernel: (optional) node_update preamble computing x_new for this
// block's 128 rows from fp32 inputs straight into the LDS GEMM tile, then
// 128x256-col GEMM. Only blockIdx.y==0 persists x_new (ping-pong); ZAGG lets
// fng2's y==0 blocks re-zero aggA for the layer-2 agg pass.
// ---------------------------------------------------------------------------
template <bool UPD, bool WRX, bool ZAGG>
__global__ __launch_bounds__(256, 2) void k_fng(
    const float* __restrict__ xfPrev, const unsigned short* __restrict__ XWprev,
    const float* __restrict__ aggRd, float* __restrict__ xfNext,
    float* __restrict__ aggZ, const unsigned short* __restrict__ WTp,
    const unsigned short* __restrict__ bias, unsigned short* __restrict__ out,
    int out_pitch) {
  __shared__ int4 sm4[128 * 33];
  char* smc = (char*)sm4;
  const long tileBase = (long)blockIdx.x * 128;
  const int tid = threadIdx.x;
  {
#pragma unroll
    for (int it = 0; it < 32; ++it) {  // 128 rows x 64 col-groups of 4 floats
      int lin = it * 256 + tid;
      int row = lin >> 6, cg = lin & 63;
      long rg = tileBase + row;
      if (rg > N_NODES - 1) rg = N_NODES - 1;
      long idx = (rg << 8) + cg * 4;
      fp32x4 xn = *(const fp32x4*)(xfPrev + idx);
      if (UPD) {
        fp32x4 a4 = *(const fp32x4*)(aggRd + idx);
        u16x4 w4 = *(const u16x4*)(XWprev + (rg << 10) + cg * 4);
#pragma unroll
        for (int j = 0; j < 4; ++j) {
          float t = bf2f(w4[j]) + a4[j];
          xn[j] = xn[j] + fmaxf(t, 0.f);
        }
        if (WRX && blockIdx.y == 0) *(fp32x4*)(xfNext + idx) = xn;
      }
      if (ZAGG && blockIdx.y == 0) {
        fp32x4 z4 = {0.f, 0.f, 0.f, 0.f};
        *(fp32x4*)(aggZ + idx) = z4;
      }
      unsigned int w0 = f2bf_pk(xn[0], xn[1]);
      unsigned int w1 = f2bf_pk(xn[2], xn[3]);
      unsigned int* dst = (unsigned int*)(smc + row * SM_PITCH + cg * 8);
      dst[0] = w0;
      dst[1] = w1;
    }
  }
  __syncthreads();
  fp32x4 acc[4][8];
#pragma unroll
  for (int mt = 0; mt < 4; ++mt)
#pragma unroll
    for (int nt = 0; nt < 8; ++nt) acc[mt][nt] = 0.f;
  const int wave = tid >> 6, lane = tid & 63;
  const int q = lane >> 4, ll = lane & 15;
  const int colBase = blockIdx.y * 256 + wave * 64;
  gemm_swap<4, 8>(smc, WTp, colBase, acc);

  const int cb = colBase + q * 16;
  u16x8 bs0 = *(const u16x8*)(bias + cb);
  u16x8 bs1 = *(const u16x8*)(bias + cb + 8);
#pragma unroll
  for (int nt = 0; nt < 8; ++nt) {
    long nn = tileBase + nt * 16 + ll;
    if (nn >= N_NODES) continue;
    float f[16];
#pragma unroll
    for (int mt = 0; mt < 4; ++mt)
#pragma unroll
      for (int r = 0; r < 4; ++r) {
        int i = mt * 4 + r;
        float bv = bf2f(i < 8 ? bs0[i] : bs1[i - 8]);
        f[i] = acc[mt][nt][r] + bv;
      }
    union { u16x8 v; unsigned int w[4]; } O0, O1;
#pragma unroll
    for (int p = 0; p < 4; ++p) {
      O0.w[p] = f2bf_pk(f[2 * p], f[2 * p + 1]);
      O1.w[p] = f2bf_pk(f[8 + 2 * p], f[9 + 2 * p]);
    }
    *(u16x8*)(out + nn * out_pitch + cb) = O0.v;
    *(u16x8*)(out + nn * out_pitch + cb + 8) = O1.v;
  }
}

// ---------------------------------------------------------------------------
// Edge-tiled agg: block = 64 consecutive CSR rows, loads batched 8-wide,
// one atomicAdd per dst-run. Sits at its 164MB e-read HBM floor (~33us).
// ---------------------------------------------------------------------------
template <bool FIRST>
__global__ void k_agg(const int* __restrict__ csrc, const int* __restrict__ cdst,
                      const unsigned short* __restrict__ e,
                      const unsigned short* __restrict__ eaC,
                      const unsigned short* __restrict__ arena,
                      const unsigned short* __restrict__ XW, int xw_pitch, int x2_off,
                      float* __restrict__ agg) {
  __shared__ int s_src[64];
  __shared__ int s_dst[64];
  const long base = (long)blockIdx.x * 64;
  const int c = threadIdx.x;
  if (c < 64) {
    long r = base + c;
    int s = csrc[r]; if ((unsigned)s >= N_NODES) s = 0;
    int d = cdst[r]; if ((unsigned)d >= N_NODES) d = 0;
    s_src[c] = s;
    s_dst[c] = d;
  }
  __syncthreads();
  float wac = 0.f, bac = 0.f;
  if (FIRST) { wac = bf2f(arena[A_WA + c]); bac = bf2f(arena[A_BA + c]); }
  float a = 0.f;
  int run = s_dst[0];
  for (int b8 = 0; b8 < 64; b8 += 8) {
    float evv[8], x2v[8];
#pragma unroll
    for (int j = 0; j < 8; ++j) {
      int row = b8 + j;
      if (FIRST) evv[j] = fmaf(bf2f(eaC[base + row]), wac, bac);
      else evv[j] = bf2f(__builtin_nontemporal_load(e + ((base + row) << 8) + c));
      x2v[j] = bf2f(XW[(long)s_src[row] * xw_pitch + x2_off + c]);
    }
#pragma unroll
    for (int j = 0; j < 8; ++j) {
      int d = s_dst[b8 + j];
      if (d != run) {  // uniform across the block (dst-sorted)
        atomicAdd(&agg[((long)run << 8) + c], a);
        a = 0.f;
        run = d;
      }
      a = fmaf(fsigmoid(evv[j]), x2v[j], a);
    }
  }
  atomicAdd(&agg[((long)run << 8) + c], a);
}

// ---------------------------------------------------------------------------
extern "C" void kernel_launch(void* const* d_in, const int* in_sizes, int n_in,
                              void* d_out, int out_size, void* d_ws, size_t ws_size,
                              hipStream_t stream) {
  const int* eidx = (const int*)d_in[2];
  const int* srcA = eidx;
  const int* dstA = eidx + N_EDGES;
  (void)in_sizes; (void)n_in; (void)out_size;

  char* ws = (char*)d_ws;
  size_t off = 0;
  auto alloc = [&](size_t bytes) -> char* {
    char* p = ws + off;
    off = (off + bytes + 255) & ~(size_t)255;
    return p;
  };
  unsigned short* e_buf   = (unsigned short*)alloc((size_t)N_EDGES * 256 * 2);  // 164 MB
  float*          xfA     = (float*)alloc((size_t)N_NODES * 256 * 4);
  unsigned short* XWa     = (unsigned short*)alloc((size_t)N_NODES * 1024 * 2);
  unsigned short* XWb     = (unsigned short*)alloc((size_t)N_NODES * 1024 * 2);
  unsigned short* XW3     = (unsigned short*)alloc((size_t)N_NODES * 512 * 2);
  float*          xfB     = (float*)XW3;   // alias: lifetimes disjoint (x1 dead
                                           // before XW3 is written in fng3)
  float*          aggA    = (float*)alloc((size_t)N_NODES * 256 * 4);
  float*          aggB    = (float*)alloc((size_t)N_NODES * 256 * 4);
  unsigned short* nodeBT  = (unsigned short*)alloc((size_t)917504 * 2);
  unsigned short* WeT     = (unsigned short*)alloc((size_t)4 * 65536 * 2);
  unsigned short* Wm1T    = (unsigned short*)alloc((size_t)32768 * 2);
  unsigned short* nodeBTp = (unsigned short*)alloc((size_t)917504 * 2);
  unsigned short* WeTp    = (unsigned short*)alloc((size_t)4 * 65536 * 2);
  unsigned short* Wm1Tp   = (unsigned short*)alloc((size_t)32768 * 2);
  unsigned short* biascat = (unsigned short*)alloc((size_t)3584 * 2);
  unsigned short* arena   = (unsigned short*)alloc((size_t)ARENA_TOT * 2);
  int* deg    = (int*)alloc((size_t)N_NODES * 4);
  int* rowptr = (int*)alloc((size_t)(N_NODES + 1) * 4);
  int* cursor = (int*)alloc((size_t)N_NODES * 4);
  int* eid    = (int*)alloc((size_t)N_EDGES * 4);
  int* csrc   = (int*)alloc((size_t)N_EDGES * 4);
  int* cdst   = (int*)alloc((size_t)N_EDGES * 4);
  unsigned short* eaC = (unsigned short*)alloc((size_t)N_EDGES * 2);
  int* flag   = (int*)alloc(4);
  if (ws_size < off) return;  // distinctive signature: out stays all-zero

  Ptrs ptrs;
  {
    int map[19] = {0, 1, 3, 4, 5, 6, 7, 8, 9, 10, 11, 12, 13, 14, 15, 16, 17, 18, 19};
    for (int j = 0; j < 19; ++j) ptrs.p[j] = d_in[map[j]];
  }

  dim3 blk(256);
  k_detect<<<dim3(40), blk, 0, stream>>>((const unsigned short*)d_in[3], flag, deg);
  // cast + hist (deg zeroed by k_detect, stream-ordered)
  k_cast<<<dim3((ARENA_USED + 255) / 256), blk, 0, stream>>>(ptrs, flag, arena,
                                                             dstA, deg);
  k_prep<<<dim3(256, 1, 20), blk, 0, stream>>>(arena, nodeBT, WeT, Wm1T, biascat);
  k_pack_all<<<dim3((PK_NODE + PK_WE + PK_WM1 + 255) / 256), blk, 0, stream>>>(
      nodeBT, nodeBTp, WeT, WeTp, Wm1T, Wm1Tp);
  k_init_x<<<dim3(N_NODES), blk, 0, stream>>>(arena, xfA, aggA, aggB);
  k_scan<<<dim3(1), blk, 0, stream>>>(deg, rowptr, cursor);
  k_fill<<<dim3(N_EDGES / 256), blk, 0, stream>>>(dstA, srcA, arena, cursor, eid, csrc,
                                                  cdst, eaC);

  // ng0: XWa = x0 @ nodeBT0
  k_fng<false, false, false><<<dim3(79, 4), blk, 0, stream>>>(
      xfA, nullptr, nullptr, nullptr, nullptr, nodeBTp, biascat, XWa, 1024);
  // agg(0) -> aggA
  k_agg<true><<<dim3(N_EDGES / 64), blk, 0, stream>>>(csrc, cdst, e_buf, eaC, arena,
                                                      XWa, 1024, 256, aggA);
  // fng1: x1 = upd(x0, XWa, aggA) -> xfB; XWb = x1 @ nodeBT1
  k_fng<true, true, false><<<dim3(79, 4), blk, 0, stream>>>(
      xfA, XWa, aggA, xfB, nullptr, nodeBTp + 262144, biascat + 1024, XWb, 1024);
  // fused edge layers 0+1 (+ inlined agg(1) -> aggB); writes only e2
  k_edge01<<<dim3(EDGE_BLOCKS), blk, 0, stream>>>(
      e_buf, WeTp, WeTp + 65536, XWa, XWb, arena, eaC, csrc, cdst, aggB);
  // fng2: x2 = upd(x1, XWb, aggB) -> xfA; XWa = x2 @ nodeBT2; zero aggA
  k_fng<true, true, true><<<dim3(79, 4), blk, 0, stream>>>(
      xfB, XWb, aggB, xfA, aggA, nodeBTp + 2 * 262144, biascat + 2048, XWa, 1024);
  // agg(2) from e2 -> aggA
  k_agg<false><<<dim3(N_EDGES / 64), blk, 0, stream>>>(csrc, cdst, e_buf, eaC, arena,
                                                       XWa, 1024, 256, aggA);
  // fng3: x3 = upd(x2, XWa, aggA) (not persisted); XW3 = x3 @ [Ws3|Wt3]
  k_fng<true, false, false><<<dim3(79, 2), blk, 0, stream>>>(
      xfA, XWa, aggA, nullptr, nullptr, nodeBTp + 786432, biascat + 3072, XW3, 512);
  // fused edge layers 2+3 + MLP head
  k_edge_last2<<<dim3(EDGE_BLOCKS), blk, 0, stream>>>(
      e_buf, WeTp + 2 * 65536, WeTp + 3 * 65536, XWa, XW3, arena, eaC,
      csrc, cdst, Wm1Tp, eid, flag, d_out);
}

// Round 16
// 712.833 us; speedup vs baseline: 1.0168x; 1.0168x over previous
//
#include <hip/hip_runtime.h>
#include <hip/hip_bf16.h>
#include <stdint.h>

#define N_NODES 10000
#define N_EDGES 320000

using bf16x8 = __attribute__((ext_vector_type(8))) short;
using fp32x4 = __attribute__((ext_vector_type(4))) float;
using u16x8 = __attribute__((ext_vector_type(8))) unsigned short;
using u16x4 = __attribute__((ext_vector_type(4))) unsigned short;
using i32x4 = __attribute__((ext_vector_type(4))) int;

__device__ __forceinline__ float bf2f(unsigned short u) {
  union { unsigned int i; float f; } v; v.i = ((unsigned int)u) << 16; return v.f;
}
__device__ __forceinline__ unsigned short f2bf(float f) {
  union { float f; unsigned int i; } v; v.f = f;
  unsigned int x = v.i;
  x += 0x7fffu + ((x >> 16) & 1u);
  return (unsigned short)(x >> 16);
}
// Packed f32x2 -> bf16x2 via v_cvt_pk_bf16_f32 (RNE, same rounding as f2bf).
__device__ __forceinline__ unsigned int f2bf_pk(float lo, float hi) {
  __hip_bfloat162 h = __float22bfloat162_rn(float2{lo, hi});
  union { __hip_bfloat162 h; unsigned int u; } cv; cv.h = h; return cv.u;
}
// Fast sigmoid: raw v_rcp_f32 (~1ulp) -- fine vs 0.03 absmax tolerance.
__device__ __forceinline__ float fsigmoid(float x) {
  return __builtin_amdgcn_rcpf(1.f + __expf(-x));
}

// ---------------- internal bf16 arena (element offsets) ---------------------
#define A_POS 0
#define A_EA 20000
#define A_WP 340000
#define A_BP 340512
#define A_WA 340768
#define A_BA 341024
#define A_W1 341280
#define A_B1 537888
#define A_W2 538656
#define A_B2 735264
#define A_WE 736032
#define A_BE 998176
#define A_WS 999200
#define A_WT 1261344
#define A_WM1 1523488
#define A_BM1 1556384
#define A_AL 1556512
#define A_WM2 1556544
#define A_BM2 1556672
#define ARENA_USED 1556673
#define ARENA_TOT 1556736

__constant__ int g_off[19] = {A_POS, A_EA, A_WP, A_BP, A_WA, A_BA, A_W1, A_B1,
                              A_W2, A_B2, A_WE, A_BE, A_WS, A_WT, A_WM1,
                              A_BM1, A_AL, A_WM2, A_BM2};

struct Ptrs { const void* p[19]; };

// Dtype detector (block 0) + deg zeroing (all blocks).
__global__ void k_detect(const unsigned short* wpraw, int* flag, int* deg) {
  int i = blockIdx.x * 256 + threadIdx.x;
  if (i < N_NODES) deg[i] = 0;
  if (blockIdx.x == 0) {
    __shared__ int cnt;
    int tid = threadIdx.x;
    if (tid == 0) cnt = 0;
    __syncthreads();
    float v0 = bf2f(wpraw[tid]);
    float v1 = bf2f(wpraw[256 + tid]);
    int big = (fabsf(v0) > 100.f ? 1 : 0) + (fabsf(v1) > 100.f ? 1 : 0);
    atomicAdd(&cnt, big);
    __syncthreads();
    if (tid == 0) *flag = (cnt > 10) ? 1 : 0;  // 1 = fp32 inputs
  }
}

// Normalize all float inputs into the bf16 arena (flattened grid).
// k_hist folded in (edge indices 0..N_EDGES-1 are all < ARENA_USED; deg
// zeroed by the earlier k_detect launch) -- saves one launch.
__global__ void k_cast(Ptrs ptrs, const int* __restrict__ flag,
                       unsigned short* __restrict__ arena,
                       const int* __restrict__ dstA, int* __restrict__ deg) {
  int a = blockIdx.x * 256 + threadIdx.x;
  if (a >= ARENA_USED) return;
  if (a < N_EDGES) {
    int d = dstA[a];
    if ((unsigned)d < N_NODES) atomicAdd(&deg[d], 1);
  }
  int z = 0;
#pragma unroll
  for (int j = 1; j < 19; ++j) if (a >= g_off[j]) z = j;
  int i = a - g_off[z];
  float v;
  if (*flag) v = ((const float*)ptrs.p[z])[i];
  else       v = bf2f(((const unsigned short*)ptrs.p[z])[i]);
  arena[a] = f2bf(v);
}

// ---------------------------------------------------------------------------
// Weight prep: transpose [K,N] -> n-major [N,K] (row = out-col, 512B rows).
// nodeBT per layer l<3: [W1T|W2T|WsT|WtT] (1024x256); l==3: [WsT|WtT].
// ---------------------------------------------------------------------------
__global__ void k_prep(const unsigned short* __restrict__ arena,
                       unsigned short* nodeBT, unsigned short* WeT,
                       unsigned short* Wm1T, unsigned short* biascat) {
  int z = blockIdx.z;
  int i = blockIdx.x * 256 + threadIdx.x;
  if (z == 19) {  // bias concat: 3 x [b1|b2|0|0] (1024) then 512 zeros
    if (i < 3072) {
      int l = i >> 10, j = i & 1023;
      unsigned short v = 0;
      if (j < 256) v = arena[A_B1 + l * 256 + j];
      else if (j < 512) v = arena[A_B2 + l * 256 + (j - 256)];
      biascat[i] = v;
    } else if (i < 3584) {
      biascat[i] = 0;
    }
    return;
  }
  const unsigned short* src; unsigned short* dst; int srcN = 256;
  if (z < 3)       {                 src = arena + A_W1 + z * 65536; dst = nodeBT + z * 262144; }
  else if (z < 6)  { int l = z - 3;  src = arena + A_W2 + l * 65536; dst = nodeBT + l * 262144 + 65536; }
  else if (z < 10) { int l = z - 6;  src = arena + A_WS + l * 65536;
                     dst = (l < 3) ? nodeBT + l * 262144 + 131072 : nodeBT + 786432; }
  else if (z < 14) { int l = z - 10; src = arena + A_WT + l * 65536;
                     dst = (l < 3) ? nodeBT + l * 262144 + 196608 : nodeBT + 786432 + 65536; }
  else if (z < 18) { int l = z - 14; src = arena + A_WE + l * 65536; dst = WeT + l * 65536; }
  else             { src = arena + A_WM1; dst = Wm1T; srcN = 128; }
  if (i < srcN * 256) {
    int k = i & 255, n = i >> 8;
    dst[i] = src[k * srcN + n];  // dst[n][k] = src[k][n]
  }
}

// ---------------------------------------------------------------------------
// Fragment pack, ALL THREE weight families in one launch.
// ---------------------------------------------------------------------------
#define PK_NODE 114688
#define PK_WE   32768
#define PK_WM1  4096
__global__ void k_pack_all(const unsigned short* __restrict__ nodeBT,
                           unsigned short* __restrict__ nodeBTp,
                           const unsigned short* __restrict__ WeT,
                           unsigned short* __restrict__ WeTp,
                           const unsigned short* __restrict__ Wm1T,
                           unsigned short* __restrict__ Wm1Tp) {
  int gc = blockIdx.x * 256 + threadIdx.x;
  const unsigned short* src; unsigned short* dst; int MT; int c;
  if (gc < PK_NODE)                { src = nodeBT; dst = nodeBTp; MT = 4; c = gc; }
  else if (gc < PK_NODE + PK_WE)   { src = WeT;  dst = WeTp;  MT = 4; c = gc - PK_NODE; }
  else if (gc < PK_NODE + PK_WE + PK_WM1)
                                   { src = Wm1T; dst = Wm1Tp; MT = 2; c = gc - PK_NODE - PK_WE; }
  else return;
  int perg = MT * 512;               // 16B chunks per group
  int g = c / perg, r = c % perg;
  int ks = r / (64 * MT);
  int rem = r % (64 * MT);
  int mt = rem >> 6, lane = rem & 63;
  int q = lane >> 4, ll = lane & 15;
  int oc = g * (MT * 16) + (ll >> 2) * (MT * 4) + (ll & 3) + mt * 4;
  i32x4 v = *(const i32x4*)((const char*)src + ((long)oc << 9) + (ks << 6) + (q << 4));
  ((i32x4*)dst)[c] = v;
}

// x0 = pos @ Wp + bp (K=2), fp32 master; zeroes BOTH agg buffers.
__global__ void k_init_x(const unsigned short* __restrict__ arena,
                         float* __restrict__ xf, float* __restrict__ aggA,
                         float* __restrict__ aggB) {
  int n = blockIdx.x, c = threadIdx.x;
  float p0 = bf2f(arena[A_POS + 2 * n]), p1 = bf2f(arena[A_POS + 2 * n + 1]);
  float v = fmaf(p0, bf2f(arena[A_WP + c]),
                 fmaf(p1, bf2f(arena[A_WP + 256 + c]), bf2f(arena[A_BP + c])));
  long idx = ((long)n << 8) + c;
  xf[idx] = v;
  aggA[idx] = 0.f;
  aggB[idx] = 0.f;
}

__global__ void k_scan(const int* __restrict__ deg, int* __restrict__ rowptr,
                       int* __restrict__ cursor) {
  __shared__ int part[256];
  int tid = threadIdx.x;
  int base = tid * 40;
  int s = 0;
  for (int i = 0; i < 40; ++i) {
    int idx = base + i;
    if (idx < N_NODES) s += deg[idx];
  }
  part[tid] = s;
  __syncthreads();
  if (tid == 0) {
    int run = 0;
    for (int i = 0; i < 256; ++i) { int t = part[i]; part[i] = run; run += t; }
    rowptr[N_NODES] = run;
  }
  __syncthreads();
  int run = part[tid];
  for (int i = 0; i < 40; ++i) {
    int idx = base + i;
    if (idx < N_NODES) { rowptr[idx] = run; cursor[idx] = run; run += deg[idx]; }
  }
}

// Also emits csrc/cdst (endpoints in CSR order) and eaC (ea gathered to CSR).
__global__ void k_fill(const int* __restrict__ dstA, const int* __restrict__ srcA,
                       const unsigned short* __restrict__ arena,
                       int* __restrict__ cursor, int* __restrict__ eid,
                       int* __restrict__ csrc, int* __restrict__ cdst,
                       unsigned short* __restrict__ eaC) {
  int i = blockIdx.x * 256 + threadIdx.x;
  if (i < N_EDGES) {
    int d = dstA[i]; if ((unsigned)d >= N_NODES) d = 0;
    int p = atomicAdd(&cursor[d], 1);
    if ((unsigned)p < N_EDGES) {
      eid[p] = i;
      int s = srcA[i]; if ((unsigned)s >= N_NODES) s = 0;
      csrc[p] = s;
      cdst[p] = d;
      eaC[p] = arena[A_EA + i];
    }
  }
}

// ---------------------------------------------------------------------------
// Round 16 = best-of recombination: round-14's edge kernels EXACTLY (8-wide
// agg batches -- r15's 4-wide cost 10us of memory-level parallelism and did
// NOT change WRITE_SIZE, falsifying the spill theory) + r15's launch merges
// (k_hist folded into k_cast; single k_pack_all). r14 measured 720.7us.
// HARD RULE (r4/r6/r10/r12/r13): no widened temporaries or register-resident
// prefetch in the edge kernels; scalar epilogue only.
// ---------------------------------------------------------------------------
#define SM_PITCH 528
#define XS_PITCH 144
#define EROWS 80
#define ECHUNKS 5
#define EDGE_BLOCKS (N_EDGES / EROWS)   // 4000

template <bool NT, int ROWS, int BLK>
__device__ __forceinline__ void stage_tile(char* smc, const unsigned short* src,
                                           long rowBase) {
  int tid = threadIdx.x;
#pragma unroll
  for (int it = 0; it < ROWS * 32 / BLK; ++it) {   // ROWS rows x 32 groups of 16B
    int lin = it * BLK + tid;
    int row = lin >> 5, g = lin & 31;
    const i32x4* p = (const i32x4*)((const char*)src + ((rowBase + row) << 9) + (g << 4));
    i32x4 v = NT ? __builtin_nontemporal_load(p) : *p;
    *(i32x4*)(smc + row * SM_PITCH + (g << 4)) = v;
  }
}

template <int MT, int NTT>
__device__ __forceinline__ void gemm_swap(const char* smc, const unsigned short* WTp,
                                          int colBase, fp32x4 (&acc)[MT][NTT]) {
  const int lane = threadIdx.x & 63;
  const int q = lane >> 4, ll = lane & 15;
  const char* wbase = (const char*)WTp + ((long)colBase << 9) + (lane << 4);
  __builtin_amdgcn_s_setprio(1);
#pragma unroll
  for (int ks = 0; ks < 8; ++ks) {
    bf16x8 a[MT];
#pragma unroll
    for (int mt = 0; mt < MT; ++mt)
      a[mt] = *(const bf16x8*)(wbase + ((long)(ks * MT + mt) << 10));
    bf16x8 b[NTT];
#pragma unroll
    for (int nt = 0; nt < NTT; ++nt)
      b[nt] = *(const bf16x8*)(smc + (nt * 16 + ll) * SM_PITCH + (ks << 6) + (q << 4));
#pragma unroll
    for (int mt = 0; mt < MT; ++mt)
#pragma unroll
      for (int nt = 0; nt < NTT; ++nt)
        acc[mt][nt] = __builtin_amdgcn_mfma_f32_16x16x32_bf16(a[mt], b[nt], acc[mt][nt], 0, 0, 0);
  }
  __builtin_amdgcn_s_setprio(0);
}

// ---------------------------------------------------------------------------
// Edge epilogue with COALESCED xs gather (1-chunk-ahead LDS bounce pipeline);
// xt direct. e_new = e_old + relu(acc + xs + xt + be), in-place in LDS tile.
// Output packing via v_cvt_pk_bf16_f32. (scalar round-9 version, scratch-free)
// ---------------------------------------------------------------------------
template <int NTT>
__device__ __forceinline__ void edge_epilogue_cx(
    char* smc, char* xsw, const fp32x4 (&acc)[4][NTT], const int* s_src,
    const int* s_dst, const unsigned short* XW, int xw_pitch, int xs_off,
    int xt_off, const unsigned short* bePtr, int colBase, int lane) {
  const int q = lane >> 4, ll = lane & 15;
  const int cb = colBase + q * 16;
  u16x8 be0 = *(const u16x8*)(bePtr + cb);
  u16x8 be1 = *(const u16x8*)(bePtr + cb + 8);
  const int prow = lane >> 3;          // row within half-chunk (0..7)
  const int ppc = lane & 7;            // 16B piece within row
  const int pcol = xs_off + colBase + ppc * 8;
  u16x8 pfA = *(const u16x8*)(XW + (long)s_src[prow] * xw_pitch + pcol);
  u16x8 pfB = *(const u16x8*)(XW + (long)s_src[8 + prow] * xw_pitch + pcol);
#pragma unroll
  for (int nt = 0; nt < NTT; ++nt) {
    *(u16x8*)(xsw + prow * XS_PITCH + ppc * 16) = pfA;
    *(u16x8*)(xsw + (8 + prow) * XS_PITCH + ppc * 16) = pfB;
    if (nt + 1 < NTT) {   // issue next chunk's gathers; they fly under compute
      int elA = (nt + 1) * 16 + prow;
      pfA = *(const u16x8*)(XW + (long)s_src[elA] * xw_pitch + pcol);
      pfB = *(const u16x8*)(XW + (long)s_src[elA + 8] * xw_pitch + pcol);
    }
    int el = nt * 16 + ll;
    int dn = s_dst[el];
    const unsigned short* xtrow = XW + (long)dn * xw_pitch + xt_off + cb;
    u16x8 xt0 = *(const u16x8*)(xtrow);
    u16x8 xt1 = *(const u16x8*)(xtrow + 8);
    u16x8 xs0 = *(const u16x8*)(xsw + ll * XS_PITCH + q * 32);
    u16x8 xs1 = *(const u16x8*)(xsw + ll * XS_PITCH + q * 32 + 16);
    u16x8* slot = (u16x8*)(smc + el * SM_PITCH + cb * 2);
    u16x8 er0 = slot[0], er1 = slot[1];
    float f[16];
#pragma unroll
    for (int mt = 0; mt < 4; ++mt)
#pragma unroll
      for (int r = 0; r < 4; ++r) {
        int i = mt * 4 + r;
        float xsv = bf2f(i < 8 ? xs0[i] : xs1[i - 8]);
        float xtv = bf2f(i < 8 ? xt0[i] : xt1[i - 8]);
        float erv = bf2f(i < 8 ? er0[i] : er1[i - 8]);
        float bev = bf2f(i < 8 ? be0[i] : be1[i - 8]);
        float v = acc[mt][nt][r] + xsv + xtv + bev;
        v = fmaxf(v, 0.f);
        f[i] = erv + v;
      }
    union { u16x8 v; unsigned int w[4]; } O0, O1;
#pragma unroll
    for (int p = 0; p < 4; ++p) {
      O0.w[p] = f2bf_pk(f[2 * p], f[2 * p + 1]);
      O1.w[p] = f2bf_pk(f[8 + 2 * p], f[9 + 2 * p]);
    }
    slot[0] = O0.v;
    slot[1] = O1.v;  // slot owned by this lane only
  }
}

// ---------------------------------------------------------------------------
// Fused layers-0+1 edge kernel (80-row tiles, 3 blocks/CU): build e0 from
// eaC; edge(0) -> e1 in LDS; agg(1) from the e1 tile (single-chain scan,
// 8-wide batches, run-batched atomics into aggB); edge(1) -> e2 in LDS;
// write e2. e1 never hits HBM.
// ---------------------------------------------------------------------------
__global__ __launch_bounds__(256, 3) void k_edge01(
    unsigned short* __restrict__ e, const unsigned short* __restrict__ WeT0,
    const unsigned short* __restrict__ WeT1,
    const unsigned short* __restrict__ XWa, const unsigned short* __restrict__ XWb,
    const unsigned short* __restrict__ arena, const unsigned short* __restrict__ eaC,
    const int* __restrict__ csrc, const int* __restrict__ cdst,
    float* __restrict__ agg) {
  __shared__ int4 sm4[EROWS * 33];
  __shared__ int4 xsb4[4 * 2304 / 16];
  __shared__ int s_src[EROWS];
  __shared__ int s_dst[EROWS];
  char* smc = (char*)sm4;
  const long tileBase = (long)blockIdx.x * EROWS;
  const int tid = threadIdx.x;
  const int wave = tid >> 6, lane = tid & 63;
  const int colBase = wave * 64;
  char* xsw = (char*)xsb4 + wave * 2304;

  // ---- build e0 = ea*Wa + ba in LDS ----
#pragma unroll
  for (int it = 0; it < EROWS * 32 / 256; ++it) {
    int lin = it * 256 + tid;
    int row = lin >> 5, g = lin & 31;
    float eav = bf2f(eaC[tileBase + row]);
    int c0 = g * 8;
    float f[8];
#pragma unroll
    for (int j = 0; j < 8; ++j)
      f[j] = fmaf(eav, bf2f(arena[A_WA + c0 + j]), bf2f(arena[A_BA + c0 + j]));
    union { bf16x8 v; unsigned int w[4]; } O;
#pragma unroll
    for (int p = 0; p < 4; ++p) O.w[p] = f2bf_pk(f[2 * p], f[2 * p + 1]);
    *(bf16x8*)(smc + row * SM_PITCH + (g << 4)) = O.v;
  }
  if (tid < EROWS) {
    long edge = tileBase + tid;
    int s = csrc[edge]; if ((unsigned)s >= N_NODES) s = 0;
    int d = cdst[edge]; if ((unsigned)d >= N_NODES) d = 0;
    s_src[tid] = s;
    s_dst[tid] = d;
  }
  __syncthreads();

  // ---- edge update l=0 -> e1 in LDS ----
  fp32x4 acc[4][ECHUNKS];
#pragma unroll
  for (int mt = 0; mt < 4; ++mt)
#pragma unroll
    for (int nt = 0; nt < ECHUNKS; ++nt) acc[mt][nt] = 0.f;
  gemm_swap<4, ECHUNKS>(smc, WeT0, colBase, acc);
  __syncthreads();
  edge_epilogue_cx<ECHUNKS>(smc, xsw, acc, s_src, s_dst, XWa, 1024, 512, 768,
                            arena + A_BE, colBase, lane);
  __syncthreads();  // e1 complete in LDS

  // ---- agg(1): gate(e1) * (x1@W2+b2)[src], run-batched atomics ----
  {
    const int c = tid;           // column 0..255
    float a = 0.f;
    int run = s_dst[0];
    for (int b8 = 0; b8 < EROWS; b8 += 8) {
      float evv[8], x2v[8];
#pragma unroll
      for (int j = 0; j < 8; ++j) {
        int row = b8 + j;
        evv[j] = bf2f(*(const unsigned short*)(smc + row * SM_PITCH + c * 2));
        x2v[j] = bf2f(XWb[(long)s_src[row] * 1024 + 256 + c]);
      }
#pragma unroll
      for (int j = 0; j < 8; ++j) {
        int d = s_dst[b8 + j];
        if (d != run) {  // uniform across the block (dst-sorted)
          atomicAdd(&agg[((long)run << 8) + c], a);
          a = 0.f;
          run = d;
        }
        a = fmaf(fsigmoid(evv[j]), x2v[j], a);
      }
    }
    atomicAdd(&agg[((long)run << 8) + c], a);
  }

  // ---- edge update l=1 -> e2 in LDS ----
#pragma unroll
  for (int mt = 0; mt < 4; ++mt)
#pragma unroll
    for (int nt = 0; nt < ECHUNKS; ++nt) acc[mt][nt] = 0.f;
  gemm_swap<4, ECHUNKS>(smc, WeT1, colBase, acc);
  __syncthreads();  // all waves done reading e1 tile before in-place update
  edge_epilogue_cx<ECHUNKS>(smc, xsw, acc, s_src, s_dst, XWb, 1024, 512, 768,
                            arena + A_BE + 256, colBase, lane);
  __syncthreads();  // e2 complete in LDS

  // ---- writeback e2 ----
#pragma unroll
  for (int it = 0; it < EROWS * 32 / 256; ++it) {
    int lin = it * 256 + tid;
    int row = lin >> 5, g = lin & 31;
    i32x4 v = *(const i32x4*)(smc + row * SM_PITCH + (g << 4));
    __builtin_nontemporal_store(v, (i32x4*)((char*)e + ((tileBase + row) << 9) + (g << 4)));
  }
}

// ---------------------------------------------------------------------------
// Fused last-2 edge kernel (80-row tiles, 3 blocks/CU): stage e2;
// edge-update(l=2) -> e3 in LDS; edge-update(l=3) -> e4 in LDS; fused MLP
// head -> out. e3/e4 never hit HBM.
// ---------------------------------------------------------------------------
__global__ __launch_bounds__(256, 3) void k_edge_last2(
    const unsigned short* __restrict__ e, const unsigned short* __restrict__ WeT2,
    const unsigned short* __restrict__ WeT3,
    const unsigned short* __restrict__ XW2, const unsigned short* __restrict__ XW3,
    const unsigned short* __restrict__ arena, const unsigned short* __restrict__ eaC,
    const int* __restrict__ csrc, const int* __restrict__ cdst,
    const unsigned short* __restrict__ Wm1T, const int* __restrict__ eid,
    const int* __restrict__ flag, void* __restrict__ out) {
  __shared__ int4 sm4[EROWS * 33];
  __shared__ int4 xsb4[4 * 2304 / 16];
  __shared__ int s_src[EROWS];
  __shared__ int s_dst[EROWS];
  __shared__ float part[EROWS * 4];
  char* smc = (char*)sm4;
  const long tileBase = (long)blockIdx.x * EROWS;
  const int tid = threadIdx.x;
  const int wave = tid >> 6, lane = tid & 63;
  const int q = lane >> 4, ll = lane & 15;
  const int colBase = wave * 64;
  char* xsw = (char*)xsb4 + wave * 2304;

  stage_tile<true, EROWS, 256>(smc, e, tileBase);
  if (tid < EROWS) {
    long edge = tileBase + tid;
    int s = csrc[edge]; if ((unsigned)s >= N_NODES) s = 0;
    int d = cdst[edge]; if ((unsigned)d >= N_NODES) d = 0;
    s_src[tid] = s;
    s_dst[tid] = d;
  }
  __syncthreads();

  // ---- edge update l=2 ----
  fp32x4 acc[4][ECHUNKS];
#pragma unroll
  for (int mt = 0; mt < 4; ++mt)
#pragma unroll
    for (int nt = 0; nt < ECHUNKS; ++nt) acc[mt][nt] = 0.f;
  gemm_swap<4, ECHUNKS>(smc, WeT2, colBase, acc);
  __syncthreads();
  edge_epilogue_cx<ECHUNKS>(smc, xsw, acc, s_src, s_dst, XW2, 1024, 512, 768,
                            arena + A_BE + 2 * 256, colBase, lane);
  __syncthreads();  // e3 complete in LDS

  // ---- edge update l=3 ----
#pragma unroll
  for (int mt = 0; mt < 4; ++mt)
#pragma unroll
    for (int nt = 0; nt < ECHUNKS; ++nt) acc[mt][nt] = 0.f;
  gemm_swap<4, ECHUNKS>(smc, WeT3, colBase, acc);
  __syncthreads();
  edge_epilogue_cx<ECHUNKS>(smc, xsw, acc, s_src, s_dst, XW3, 512, 0, 256,
                            arena + A_BE + 3 * 256, colBase, lane);
  __syncthreads();  // e4 complete in LDS

  // ---- fused MLP head (128 out-cols over 4 waves: 32 cols/wave) ----
  fp32x4 acc2[2][ECHUNKS];
#pragma unroll
  for (int mt = 0; mt < 2; ++mt)
#pragma unroll
    for (int nt = 0; nt < ECHUNKS; ++nt) acc2[mt][nt] = 0.f;
  const int colBase2 = wave * 32;
  gemm_swap<2, ECHUNKS>(smc, Wm1T, colBase2, acc2);

  const int cb2 = colBase2 + q * 8;
  float alphaf = bf2f(arena[A_AL]);
  float bmc[8], wl[8], w2c[8];
#pragma unroll
  for (int i = 0; i < 8; ++i) {
    bmc[i] = bf2f(arena[A_BM1 + cb2 + i]);
    wl[i] = bf2f(arena[A_WM1 + 32768 + cb2 + i]);
    w2c[i] = bf2f(arena[A_WM2 + cb2 + i]);
  }
#pragma unroll
  for (int nt = 0; nt < ECHUNKS; ++nt) {
    int el = nt * 16 + ll;
    float eav = bf2f(eaC[tileBase + el]);
    float ps = 0.f;
#pragma unroll
    for (int mt = 0; mt < 2; ++mt)
#pragma unroll
      for (int r = 0; r < 4; ++r) {
        int i = mt * 4 + r;
        float h = acc2[mt][nt][r] + bmc[i] + eav * wl[i];
        h = (h > 0.f) ? h : alphaf * h;
        ps += h * w2c[i];
      }
    ps += __shfl_xor(ps, 16, 64);
    ps += __shfl_xor(ps, 32, 64);
    if (q == 0) part[el * 4 + wave] = ps;
  }
  __syncthreads();
  if (tid < EROWS) {
    float t = part[tid * 4] + part[tid * 4 + 1] + part[tid * 4 + 2] + part[tid * 4 + 3]
            + bf2f(arena[A_BM2]);
    long row = tileBase + tid;
    int oe = eid[row]; if ((unsigned)oe >= N_EDGES) oe = 0;
    if (*flag) ((float*)out)[oe] = t;
    else       ((unsigned short*)out)[oe] = f2bf(t);
  }
}

// ---------------------------------------------------------------------------
// Fused node kernel: (optional) node_update preamble computing x_new for this
// block's 128 rows from fp32 inputs straight into the LDS GEMM tile, then
// 128x256-col GEMM. Only blockIdx.y==0 persists x_new (ping-pong); ZAGG lets
// fng2's y==0 blocks re-zero aggA for the layer-2 agg pass.
// ---------------------------------------------------------------------------
template <bool UPD, bool WRX, bool ZAGG>
__global__ __launch_bounds__(256, 2) void k_fng(
    const float* __restrict__ xfPrev, const unsigned short* __restrict__ XWprev,
    const float* __restrict__ aggRd, float* __restrict__ xfNext,
    float* __restrict__ aggZ, const unsigned short* __restrict__ WTp,
    const unsigned short* __restrict__ bias, unsigned short* __restrict__ out,
    int out_pitch) {
  __shared__ int4 sm4[128 * 33];
  char* smc = (char*)sm4;
  const long tileBase = (long)blockIdx.x * 128;
  const int tid = threadIdx.x;
  {
#pragma unroll
    for (int it = 0; it < 32; ++it) {  // 128 rows x 64 col-groups of 4 floats
      int lin = it * 256 + tid;
      int row = lin >> 6, cg = lin & 63;
      long rg = tileBase + row;
      if (rg > N_NODES - 1) rg = N_NODES - 1;
      long idx = (rg << 8) + cg * 4;
      fp32x4 xn = *(const fp32x4*)(xfPrev + idx);
      if (UPD) {
        fp32x4 a4 = *(const fp32x4*)(aggRd + idx);
        u16x4 w4 = *(const u16x4*)(XWprev + (rg << 10) + cg * 4);
#pragma unroll
        for (int j = 0; j < 4; ++j) {
          float t = bf2f(w4[j]) + a4[j];
          xn[j] = xn[j] + fmaxf(t, 0.f);
        }
        if (WRX && blockIdx.y == 0) *(fp32x4*)(xfNext + idx) = xn;
      }
      if (ZAGG && blockIdx.y == 0) {
        fp32x4 z4 = {0.f, 0.f, 0.f, 0.f};
        *(fp32x4*)(aggZ + idx) = z4;
      }
      unsigned int w0 = f2bf_pk(xn[0], xn[1]);
      unsigned int w1 = f2bf_pk(xn[2], xn[3]);
      unsigned int* dst = (unsigned int*)(smc + row * SM_PITCH + cg * 8);
      dst[0] = w0;
      dst[1] = w1;
    }
  }
  __syncthreads();
  fp32x4 acc[4][8];
#pragma unroll
  for (int mt = 0; mt < 4; ++mt)
#pragma unroll
    for (int nt = 0; nt < 8; ++nt) acc[mt][nt] = 0.f;
  const int wave = tid >> 6, lane = tid & 63;
  const int q = lane >> 4, ll = lane & 15;
  const int colBase = blockIdx.y * 256 + wave * 64;
  gemm_swap<4, 8>(smc, WTp, colBase, acc);

  const int cb = colBase + q * 16;
  u16x8 bs0 = *(const u16x8*)(bias + cb);
  u16x8 bs1 = *(const u16x8*)(bias + cb + 8);
#pragma unroll
  for (int nt = 0; nt < 8; ++nt) {
    long nn = tileBase + nt * 16 + ll;
    if (nn >= N_NODES) continue;
    float f[16];
#pragma unroll
    for (int mt = 0; mt < 4; ++mt)
#pragma unroll
      for (int r = 0; r < 4; ++r) {
        int i = mt * 4 + r;
        float bv = bf2f(i < 8 ? bs0[i] : bs1[i - 8]);
        f[i] = acc[mt][nt][r] + bv;
      }
    union { u16x8 v; unsigned int w[4]; } O0, O1;
#pragma unroll
    for (int p = 0; p < 4; ++p) {
      O0.w[p] = f2bf_pk(f[2 * p], f[2 * p + 1]);
      O1.w[p] = f2bf_pk(f[8 + 2 * p], f[9 + 2 * p]);
    }
    *(u16x8*)(out + nn * out_pitch + cb) = O0.v;
    *(u16x8*)(out + nn * out_pitch + cb + 8) = O1.v;
  }
}

// ---------------------------------------------------------------------------
// Edge-tiled agg: block = 64 consecutive CSR rows, loads batched 8-wide,
// one atomicAdd per dst-run. Sits at its 164MB e-read HBM floor (~33us).
// ---------------------------------------------------------------------------
template <bool FIRST>
__global__ void k_agg(const int* __restrict__ csrc, const int* __restrict__ cdst,
                      const unsigned short* __restrict__ e,
                      const unsigned short* __restrict__ eaC,
                      const unsigned short* __restrict__ arena,
                      const unsigned short* __restrict__ XW, int xw_pitch, int x2_off,
                      float* __restrict__ agg) {
  __shared__ int s_src[64];
  __shared__ int s_dst[64];
  const long base = (long)blockIdx.x * 64;
  const int c = threadIdx.x;
  if (c < 64) {
    long r = base + c;
    int s = csrc[r]; if ((unsigned)s >= N_NODES) s = 0;
    int d = cdst[r]; if ((unsigned)d >= N_NODES) d = 0;
    s_src[c] = s;
    s_dst[c] = d;
  }
  __syncthreads();
  float wac = 0.f, bac = 0.f;
  if (FIRST) { wac = bf2f(arena[A_WA + c]); bac = bf2f(arena[A_BA + c]); }
  float a = 0.f;
  int run = s_dst[0];
  for (int b8 = 0; b8 < 64; b8 += 8) {
    float evv[8], x2v[8];
#pragma unroll
    for (int j = 0; j < 8; ++j) {
      int row = b8 + j;
      if (FIRST) evv[j] = fmaf(bf2f(eaC[base + row]), wac, bac);
      else evv[j] = bf2f(__builtin_nontemporal_load(e + ((base + row) << 8) + c));
      x2v[j] = bf2f(XW[(long)s_src[row] * xw_pitch + x2_off + c]);
    }
#pragma unroll
    for (int j = 0; j < 8; ++j) {
      int d = s_dst[b8 + j];
      if (d != run) {  // uniform across the block (dst-sorted)
        atomicAdd(&agg[((long)run << 8) + c], a);
        a = 0.f;
        run = d;
      }
      a = fmaf(fsigmoid(evv[j]), x2v[j], a);
    }
  }
  atomicAdd(&agg[((long)run << 8) + c], a);
}

// ---------------------------------------------------------------------------
extern "C" void kernel_launch(void* const* d_in, const int* in_sizes, int n_in,
                              void* d_out, int out_size, void* d_ws, size_t ws_size,
                              hipStream_t stream) {
  const int* eidx = (const int*)d_in[2];
  const int* srcA = eidx;
  const int* dstA = eidx + N_EDGES;
  (void)in_sizes; (void)n_in; (void)out_size;

  char* ws = (char*)d_ws;
  size_t off = 0;
  auto alloc = [&](size_t bytes) -> char* {
    char* p = ws + off;
    off = (off + bytes + 255) & ~(size_t)255;
    return p;
  };
  unsigned short* e_buf   = (unsigned short*)alloc((size_t)N_EDGES * 256 * 2);  // 164 MB
  float*          xfA     = (float*)alloc((size_t)N_NODES * 256 * 4);
  unsigned short* XWa     = (unsigned short*)alloc((size_t)N_NODES * 1024 * 2);
  unsigned short* XWb     = (unsigned short*)alloc((size_t)N_NODES * 1024 * 2);
  unsigned short* XW3     = (unsigned short*)alloc((size_t)N_NODES * 512 * 2);
  float*          xfB     = (float*)XW3;   // alias: lifetimes disjoint (x1 dead
                                           // before XW3 is written in fng3)
  float*          aggA    = (float*)alloc((size_t)N_NODES * 256 * 4);
  float*          aggB    = (float*)alloc((size_t)N_NODES * 256 * 4);
  unsigned short* nodeBT  = (unsigned short*)alloc((size_t)917504 * 2);
  unsigned short* WeT     = (unsigned short*)alloc((size_t)4 * 65536 * 2);
  unsigned short* Wm1T    = (unsigned short*)alloc((size_t)32768 * 2);
  unsigned short* nodeBTp = (unsigned short*)alloc((size_t)917504 * 2);
  unsigned short* WeTp    = (unsigned short*)alloc((size_t)4 * 65536 * 2);
  unsigned short* Wm1Tp   = (unsigned short*)alloc((size_t)32768 * 2);
  unsigned short* biascat = (unsigned short*)alloc((size_t)3584 * 2);
  unsigned short* arena   = (unsigned short*)alloc((size_t)ARENA_TOT * 2);
  int* deg    = (int*)alloc((size_t)N_NODES * 4);
  int* rowptr = (int*)alloc((size_t)(N_NODES + 1) * 4);
  int* cursor = (int*)alloc((size_t)N_NODES * 4);
  int* eid    = (int*)alloc((size_t)N_EDGES * 4);
  int* csrc   = (int*)alloc((size_t)N_EDGES * 4);
  int* cdst   = (int*)alloc((size_t)N_EDGES * 4);
  unsigned short* eaC = (unsigned short*)alloc((size_t)N_EDGES * 2);
  int* flag   = (int*)alloc(4);
  if (ws_size < off) return;  // distinctive signature: out stays all-zero

  Ptrs ptrs;
  {
    int map[19] = {0, 1, 3, 4, 5, 6, 7, 8, 9, 10, 11, 12, 13, 14, 15, 16, 17, 18, 19};
    for (int j = 0; j < 19; ++j) ptrs.p[j] = d_in[map[j]];
  }

  dim3 blk(256);
  k_detect<<<dim3(40), blk, 0, stream>>>((const unsigned short*)d_in[3], flag, deg);
  // cast + hist (deg zeroed by k_detect, stream-ordered)
  k_cast<<<dim3((ARENA_USED + 255) / 256), blk, 0, stream>>>(ptrs, flag, arena,
                                                             dstA, deg);
  k_prep<<<dim3(256, 1, 20), blk, 0, stream>>>(arena, nodeBT, WeT, Wm1T, biascat);
  k_pack_all<<<dim3((PK_NODE + PK_WE + PK_WM1 + 255) / 256), blk, 0, stream>>>(
      nodeBT, nodeBTp, WeT, WeTp, Wm1T, Wm1Tp);
  k_init_x<<<dim3(N_NODES), blk, 0, stream>>>(arena, xfA, aggA, aggB);
  k_scan<<<dim3(1), blk, 0, stream>>>(deg, rowptr, cursor);
  k_fill<<<dim3(N_EDGES / 256), blk, 0, stream>>>(dstA, srcA, arena, cursor, eid, csrc,
                                                  cdst, eaC);

  // ng0: XWa = x0 @ nodeBT0
  k_fng<false, false, false><<<dim3(79, 4), blk, 0, stream>>>(
      xfA, nullptr, nullptr, nullptr, nullptr, nodeBTp, biascat, XWa, 1024);
  // agg(0) -> aggA
  k_agg<true><<<dim3(N_EDGES / 64), blk, 0, stream>>>(csrc, cdst, e_buf, eaC, arena,
                                                      XWa, 1024, 256, aggA);
  // fng1: x1 = upd(x0, XWa, aggA) -> xfB; XWb = x1 @ nodeBT1
  k_fng<true, true, false><<<dim3(79, 4), blk, 0, stream>>>(
      xfA, XWa, aggA, xfB, nullptr, nodeBTp + 262144, biascat + 1024, XWb, 1024);
  // fused edge layers 0+1 (+ inlined agg(1) -> aggB); writes only e2
  k_edge01<<<dim3(EDGE_BLOCKS), blk, 0, stream>>>(
      e_buf, WeTp, WeTp + 65536, XWa, XWb, arena, eaC, csrc, cdst, aggB);
  // fng2: x2 = upd(x1, XWb, aggB) -> xfA; XWa = x2 @ nodeBT2; zero aggA
  k_fng<true, true, true><<<dim3(79, 4), blk, 0, stream>>>(
      xfB, XWb, aggB, xfA, aggA, nodeBTp + 2 * 262144, biascat + 2048, XWa, 1024);
  // agg(2) from e2 -> aggA
  k_agg<false><<<dim3(N_EDGES / 64), blk, 0, stream>>>(csrc, cdst, e_buf, eaC, arena,
                                                       XWa, 1024, 256, aggA);
  // fng3: x3 = upd(x2, XWa, aggA) (not persisted); XW3 = x3 @ [Ws3|Wt3]
  k_fng<true, false, false><<<dim3(79, 2), blk, 0, stream>>>(
      xfA, XWa, aggA, nullptr, nullptr, nodeBTp + 786432, biascat + 3072, XW3, 512);
  // fused edge layers 2+3 + MLP head
  k_edge_last2<<<dim3(EDGE_BLOCKS), blk, 0, stream>>>(
      e_buf, WeTp + 2 * 65536, WeTp + 3 * 65536, XWa, XW3, arena, eaC,
      csrc, cdst, Wm1Tp, eid, flag, d_out);
}